// Round 5
// baseline (345.148 us; speedup 1.0000x reference)
//
#include <hip/hip_runtime.h>
#include <stdint.h>

typedef __bf16 bf16;
typedef __attribute__((ext_vector_type(4))) __bf16 bf16x4;
typedef __attribute__((ext_vector_type(8))) __bf16 bf16x8;
typedef __attribute__((ext_vector_type(4))) float f32x4;

#define B_  2
#define S_  2048
#define H_  1024
#define NH_ 16
#define HD_ 64

// ---------------------------------------------------------------------------
// GEMM: Y[m,n] = sum_k X[m,k] * W[n,k] + bias[n]   (torch Linear, B^T layout)
// 128x128 tile, BK=32, 4 waves, each wave 64x64 (4x4 of 16x16x32 MFMA).
// TX: float (converted to bf16 while staging) or bf16. TY: bf16 or float.
// W and bias are always fp32 (raw harness inputs).
// ---------------------------------------------------------------------------
template <typename TX, typename TY>
__global__ __launch_bounds__(256) void gemm_bt_bias(
    const TX* __restrict__ X,
    const float* __restrict__ W0, const float* __restrict__ W1, const float* __restrict__ W2,
    const float* __restrict__ b0, const float* __restrict__ b1, const float* __restrict__ b2,
    TY* __restrict__ Y0, TY* __restrict__ Y1, TY* __restrict__ Y2,
    int M, int N, int K)
{
  const float* W; const float* bias; TY* Y;
  if (blockIdx.z == 0)      { W = W0; bias = b0; Y = Y0; }
  else if (blockIdx.z == 1) { W = W1; bias = b1; Y = Y1; }
  else                      { W = W2; bias = b2; Y = Y2; }

  __shared__ __align__(16) bf16 As[128 * 32];
  __shared__ __align__(16) bf16 Bs[128 * 32];

  const int tid  = threadIdx.x;
  const int lane = tid & 63;
  const int wave = tid >> 6;
  const int m0 = blockIdx.y * 128;
  const int n0 = blockIdx.x * 128;
  const int wm = (wave >> 1) * 64;   // wave row offset in tile
  const int wn = (wave & 1) * 64;    // wave col offset in tile

  f32x4 acc[4][4] = {};

  for (int k0 = 0; k0 < K; k0 += 32) {
    __syncthreads();   // previous compute done before overwriting LDS

    // ---- stage A (X -> bf16 LDS) ----
    if constexpr (sizeof(TX) == 4) {
      // fp32: 128x32 tile = 1024 float4 chunks, 4 per thread
#pragma unroll
      for (int it = 0; it < 4; ++it) {
        const int c   = it * 256 + tid;       // 0..1023
        const int row = c >> 3;
        const int col = (c & 7) * 4;
        float4 v = *(const float4*)((const float*)X + (size_t)(m0 + row) * K + k0 + col);
        bf16x4 o; o[0] = (bf16)v.x; o[1] = (bf16)v.y; o[2] = (bf16)v.z; o[3] = (bf16)v.w;
        *(bf16x4*)&As[row * 32 + col] = o;
      }
    } else {
      // bf16: 128x32 tile = 512 16B chunks, 2 per thread
#pragma unroll
      for (int it = 0; it < 2; ++it) {
        const int c   = it * 256 + tid;       // 0..511
        const int row = c >> 2;
        const int col = (c & 3) * 8;
        *(bf16x8*)&As[row * 32 + col] =
            *(const bf16x8*)((const bf16*)X + (size_t)(m0 + row) * K + k0 + col);
      }
    }
    // ---- stage B (W fp32 -> bf16 LDS) ----
#pragma unroll
    for (int it = 0; it < 4; ++it) {
      const int c   = it * 256 + tid;
      const int row = c >> 3;
      const int col = (c & 7) * 4;
      float4 v = *(const float4*)(W + (size_t)(n0 + row) * K + k0 + col);
      bf16x4 o; o[0] = (bf16)v.x; o[1] = (bf16)v.y; o[2] = (bf16)v.z; o[3] = (bf16)v.w;
      *(bf16x4*)&Bs[row * 32 + col] = o;
    }
    __syncthreads();   // tiles resident

    bf16x8 a[4], b[4];
#pragma unroll
    for (int i = 0; i < 4; ++i)
      a[i] = *(const bf16x8*)&As[(wm + i * 16 + (lane & 15)) * 32 + (lane >> 4) * 8];
#pragma unroll
    for (int i = 0; i < 4; ++i)
      b[i] = *(const bf16x8*)&Bs[(wn + i * 16 + (lane & 15)) * 32 + (lane >> 4) * 8];
#pragma unroll
    for (int mi = 0; mi < 4; ++mi)
#pragma unroll
      for (int ni = 0; ni < 4; ++ni)
        acc[mi][ni] = __builtin_amdgcn_mfma_f32_16x16x32_bf16(a[mi], b[ni], acc[mi][ni], 0, 0, 0);
  }

  // epilogue: C[row=(lane>>4)*4+r][col=lane&15] per 16x16 subtile
#pragma unroll
  for (int mi = 0; mi < 4; ++mi) {
    const int row = m0 + wm + mi * 16 + (lane >> 4) * 4;
#pragma unroll
    for (int ni = 0; ni < 4; ++ni) {
      const int col = n0 + wn + ni * 16 + (lane & 15);
      const float bv = bias[col];
#pragma unroll
      for (int r = 0; r < 4; ++r)
        Y[(size_t)(row + r) * N + col] = (TY)(acc[mi][ni][r] + bv);
    }
  }
}

// ---------------------------------------------------------------------------
// Flash attention, causal. Q/K/V/O in [B*S, H] bf16, head h = cols h*64..h*64+63.
// Block: 256 threads (4 waves), one (b,h, 64-row q-tile). Wave w owns q rows
// [w*16, w*16+16). k-tiles of 64 keys, 0..qt.
// ---------------------------------------------------------------------------
__global__ __launch_bounds__(256) void attn_causal(
    const bf16* __restrict__ Q, const bf16* __restrict__ K,
    const bf16* __restrict__ V, bf16* __restrict__ O)
{
  const int qt = blockIdx.x;
  const int bh = blockIdx.y;
  const int b  = bh >> 4;
  const int h  = bh & 15;

  const int tid  = threadIdx.x;
  const int lane = tid & 63;
  const int wave = tid >> 6;
  const size_t headoff = (size_t)b * S_ * H_ + (size_t)h * HD_;
  const int q0 = qt * 64;

  __shared__ __align__(16) bf16 Qs[64 * 64];
  __shared__ __align__(16) bf16 Ks[64 * 64];
  __shared__ __align__(16) bf16 Vt[64 * 64];        // transposed: Vt[d][n]
  __shared__ __align__(16) bf16 Ps[4][16 * 64];     // per-wave P tile

  // stage Q once (64x64 = 512 16B chunks, 2 per thread)
#pragma unroll
  for (int j = 0; j < 2; ++j) {
    const int c   = tid * 2 + j;
    const int row = c >> 3;
    const int col = (c & 7) * 8;
    *(bf16x8*)&Qs[row * 64 + col] =
        *(const bf16x8*)(Q + headoff + (size_t)(q0 + row) * H_ + col);
  }

  float mrow[4], lrow[4];
  f32x4 oacc[4] = {};
#pragma unroll
  for (int r = 0; r < 4; ++r) { mrow[r] = -1e30f; lrow[r] = 0.0f; }

  for (int kt = 0; kt <= qt; ++kt) {
    const int k0 = kt * 64;
    __syncthreads();   // prev iter done reading Ks/Vt; Q writes done (iter 0)

    // stage K tile (row-major) and V transposed
#pragma unroll
    for (int j = 0; j < 2; ++j) {
      const int c   = tid * 2 + j;           // 0..511
      const int row = c >> 3;
      const int col = (c & 7) * 8;
      *(bf16x8*)&Ks[row * 64 + col] =
          *(const bf16x8*)(K + headoff + (size_t)(k0 + row) * H_ + col);
      bf16x8 v = *(const bf16x8*)(V + headoff + (size_t)(k0 + row) * H_ + col);
#pragma unroll
      for (int e = 0; e < 8; ++e)
        Vt[(col + e) * 64 + row] = v[e];
    }
    __syncthreads();

    // S = Q K^T for this wave's 16 q-rows x 64 keys
    f32x4 sacc[4] = {};
#pragma unroll
    for (int ks = 0; ks < 2; ++ks) {
      bf16x8 aq = *(const bf16x8*)&Qs[(wave * 16 + (lane & 15)) * 64 + ks * 32 + (lane >> 4) * 8];
#pragma unroll
      for (int ni = 0; ni < 4; ++ni) {
        bf16x8 bk = *(const bf16x8*)&Ks[(ni * 16 + (lane & 15)) * 64 + ks * 32 + (lane >> 4) * 8];
        sacc[ni] = __builtin_amdgcn_mfma_f32_16x16x32_bf16(aq, bk, sacc[ni], 0, 0, 0);
      }
    }

    // scale + causal mask
    float sv[4][4];                                   // [ni][r]
    const int lr0 = wave * 16 + (lane >> 4) * 4;
#pragma unroll
    for (int ni = 0; ni < 4; ++ni) {
      const int kcol = k0 + ni * 16 + (lane & 15);
#pragma unroll
      for (int r = 0; r < 4; ++r) {
        const float s = sacc[ni][r] * 0.125f;         // 1/sqrt(64)
        const int qrow = q0 + lr0 + r;
        sv[ni][r] = (kcol > qrow) ? -1e30f : s;
      }
    }

    // online softmax: row r lives in the 16 lanes sharing lane>>4
#pragma unroll
    for (int r = 0; r < 4; ++r) {
      float mx = fmaxf(fmaxf(sv[0][r], sv[1][r]), fmaxf(sv[2][r], sv[3][r]));
#pragma unroll
      for (int off = 8; off >= 1; off >>= 1)
        mx = fmaxf(mx, __shfl_xor(mx, off, 64));
      const float mnew  = fmaxf(mrow[r], mx);
      const float alpha = __expf(mrow[r] - mnew);
      float sum = 0.0f;
#pragma unroll
      for (int ni = 0; ni < 4; ++ni) {
        const float p = __expf(sv[ni][r] - mnew);
        sv[ni][r] = p;
        sum += p;
      }
#pragma unroll
      for (int off = 8; off >= 1; off >>= 1)
        sum += __shfl_xor(sum, off, 64);
      lrow[r] = lrow[r] * alpha + sum;
      mrow[r] = mnew;
#pragma unroll
      for (int dt = 0; dt < 4; ++dt) oacc[dt][r] *= alpha;
    }

    // P: C-layout regs -> A-layout via per-wave LDS round trip
#pragma unroll
    for (int ni = 0; ni < 4; ++ni)
#pragma unroll
      for (int r = 0; r < 4; ++r)
        Ps[wave][((lane >> 4) * 4 + r) * 64 + ni * 16 + (lane & 15)] = (bf16)sv[ni][r];

    // O += P V
#pragma unroll
    for (int ks = 0; ks < 2; ++ks) {
      bf16x8 ap = *(const bf16x8*)&Ps[wave][(lane & 15) * 64 + ks * 32 + (lane >> 4) * 8];
#pragma unroll
      for (int dt = 0; dt < 4; ++dt) {
        bf16x8 bv = *(const bf16x8*)&Vt[(dt * 16 + (lane & 15)) * 64 + ks * 32 + (lane >> 4) * 8];
        oacc[dt] = __builtin_amdgcn_mfma_f32_16x16x32_bf16(ap, bv, oacc[dt], 0, 0, 0);
      }
    }
  }

  // epilogue: O /= l, store
#pragma unroll
  for (int r = 0; r < 4; ++r) {
    const float inv = 1.0f / lrow[r];
    const int s = q0 + wave * 16 + (lane >> 4) * 4 + r;
#pragma unroll
    for (int dt = 0; dt < 4; ++dt) {
      const int d = dt * 16 + (lane & 15);
      O[headoff + (size_t)s * H_ + d] = (bf16)(oacc[dt][r] * inv);
    }
  }
}

extern "C" void kernel_launch(void* const* d_in, const int* in_sizes, int n_in,
                              void* d_out, int out_size, void* d_ws, size_t ws_size,
                              hipStream_t stream) {
  // inputs fp32 (reference dtype); output fp32 (reference output dtype)
  const float* hs = (const float*)d_in[0];
  const float* Wq = (const float*)d_in[1]; const float* bq = (const float*)d_in[2];
  const float* Wk = (const float*)d_in[3]; const float* bk = (const float*)d_in[4];
  const float* Wv = (const float*)d_in[5]; const float* bv = (const float*)d_in[6];
  const float* Wo = (const float*)d_in[7]; const float* bo = (const float*)d_in[8];
  float* out = (float*)d_out;

  const size_t elems = (size_t)B_ * S_ * H_;   // 4,194,304
  bf16* Qw = (bf16*)d_ws;                      // 32 MB workspace (bf16 internal)
  bf16* Kw = Qw + elems;
  bf16* Vw = Kw + elems;
  bf16* AO = Vw + elems;

  const int M = B_ * S_;   // 4096
  // QKV projections (z selects Q/K/V); fp32 in, bf16 out
  gemm_bt_bias<float, bf16><<<dim3(H_ / 128, M / 128, 3), dim3(256), 0, stream>>>(
      hs, Wq, Wk, Wv, bq, bk, bv, Qw, Kw, Vw, M, H_, H_);

  // causal flash attention (bf16 in/out)
  attn_causal<<<dim3(S_ / 64, B_ * NH_), dim3(256), 0, stream>>>(Qw, Kw, Vw, AO);

  // output projection: bf16 activations, fp32 weights, fp32 output
  gemm_bt_bias<bf16, float><<<dim3(H_ / 128, M / 128, 1), dim3(256), 0, stream>>>(
      AO, Wo, Wo, Wo, bo, bo, bo, out, out, out, M, H_, H_);
}

// Round 6
// 283.815 us; speedup vs baseline: 1.2161x; 1.2161x over previous
//
#include <hip/hip_runtime.h>
#include <stdint.h>

typedef __bf16 bf16;
typedef __attribute__((ext_vector_type(2))) __bf16 bf16x2;
typedef __attribute__((ext_vector_type(4))) __bf16 bf16x4;
typedef __attribute__((ext_vector_type(8))) __bf16 bf16x8;
typedef __attribute__((ext_vector_type(4))) float f32x4;

#define B_  2
#define S_  2048
#define H_  1024
#define NH_ 16
#define HD_ 64
#define ST  72   // padded LDS row stride (elements): 144 B, 16B-aligned, conflict-free

// ---------------------------------------------------------------------------
// GEMM: Y[m,n] = sum_k X[m,k] * W[n,k] + bias[n]   (torch Linear, B^T layout)
// 128x128 tile, BK=32, 4 waves, each wave 64x64 (4x4 of 16x16x32 MFMA).
// TX: float (converted to bf16 while staging) or bf16. TY: bf16 or float.
// Register prefetch: next tile's global loads overlap the MFMA phase.
// ---------------------------------------------------------------------------
template <typename TX, typename TY>
__global__ __launch_bounds__(256) void gemm_bt_bias(
    const TX* __restrict__ X,
    const float* __restrict__ W0, const float* __restrict__ W1, const float* __restrict__ W2,
    const float* __restrict__ b0, const float* __restrict__ b1, const float* __restrict__ b2,
    TY* __restrict__ Y0, TY* __restrict__ Y1, TY* __restrict__ Y2,
    int M, int N, int K)
{
  const float* W; const float* bias; TY* Y;
  if (blockIdx.z == 0)      { W = W0; bias = b0; Y = Y0; }
  else if (blockIdx.z == 1) { W = W1; bias = b1; Y = Y1; }
  else                      { W = W2; bias = b2; Y = Y2; }

  __shared__ __align__(16) bf16 As[128 * 32];
  __shared__ __align__(16) bf16 Bs[128 * 32];

  const int tid  = threadIdx.x;
  const int lane = tid & 63;
  const int wave = tid >> 6;
  const int m0 = blockIdx.y * 128;
  const int n0 = blockIdx.x * 128;
  const int wm = (wave >> 1) * 64;
  const int wn = (wave & 1) * 64;

  f32x4 acc[4][4] = {};

  float4 pa[4];      // fp32 A prefetch
  bf16x8 pa16[2];    // bf16 A prefetch
  float4 pb[4];      // fp32 B prefetch

  // ---- initial prefetch (k0 = 0) ----
  if constexpr (sizeof(TX) == 4) {
#pragma unroll
    for (int it = 0; it < 4; ++it) {
      const int c = it * 256 + tid, row = c >> 3, col = (c & 7) * 4;
      pa[it] = *(const float4*)((const float*)X + (size_t)(m0 + row) * K + col);
    }
  } else {
#pragma unroll
    for (int it = 0; it < 2; ++it) {
      const int c = it * 256 + tid, row = c >> 2, col = (c & 3) * 8;
      pa16[it] = *(const bf16x8*)((const bf16*)X + (size_t)(m0 + row) * K + col);
    }
  }
#pragma unroll
  for (int it = 0; it < 4; ++it) {
    const int c = it * 256 + tid, row = c >> 3, col = (c & 7) * 4;
    pb[it] = *(const float4*)(W + (size_t)(n0 + row) * K + col);
  }

  for (int k0 = 0; k0 < K; k0 += 32) {
    __syncthreads();   // previous compute done before overwriting LDS

    // ---- store prefetched tile to LDS (cvt fp32->bf16 here) ----
    if constexpr (sizeof(TX) == 4) {
#pragma unroll
      for (int it = 0; it < 4; ++it) {
        const int c = it * 256 + tid, row = c >> 3, col = (c & 7) * 4;
        bf16x4 o; o[0] = (bf16)pa[it].x; o[1] = (bf16)pa[it].y;
        o[2] = (bf16)pa[it].z; o[3] = (bf16)pa[it].w;
        *(bf16x4*)&As[row * 32 + col] = o;
      }
    } else {
#pragma unroll
      for (int it = 0; it < 2; ++it) {
        const int c = it * 256 + tid, row = c >> 2, col = (c & 3) * 8;
        *(bf16x8*)&As[row * 32 + col] = pa16[it];
      }
    }
#pragma unroll
    for (int it = 0; it < 4; ++it) {
      const int c = it * 256 + tid, row = c >> 3, col = (c & 7) * 4;
      bf16x4 o; o[0] = (bf16)pb[it].x; o[1] = (bf16)pb[it].y;
      o[2] = (bf16)pb[it].z; o[3] = (bf16)pb[it].w;
      *(bf16x4*)&Bs[row * 32 + col] = o;
    }
    __syncthreads();   // tiles resident

    // ---- issue next tile's loads (overlap with MFMA below) ----
    if (k0 + 32 < K) {
      if constexpr (sizeof(TX) == 4) {
#pragma unroll
        for (int it = 0; it < 4; ++it) {
          const int c = it * 256 + tid, row = c >> 3, col = (c & 7) * 4;
          pa[it] = *(const float4*)((const float*)X + (size_t)(m0 + row) * K + k0 + 32 + col);
        }
      } else {
#pragma unroll
        for (int it = 0; it < 2; ++it) {
          const int c = it * 256 + tid, row = c >> 2, col = (c & 3) * 8;
          pa16[it] = *(const bf16x8*)((const bf16*)X + (size_t)(m0 + row) * K + k0 + 32 + col);
        }
      }
#pragma unroll
      for (int it = 0; it < 4; ++it) {
        const int c = it * 256 + tid, row = c >> 3, col = (c & 7) * 4;
        pb[it] = *(const float4*)(W + (size_t)(n0 + row) * K + k0 + 32 + col);
      }
    }

    bf16x8 a[4], b[4];
#pragma unroll
    for (int i = 0; i < 4; ++i)
      a[i] = *(const bf16x8*)&As[(wm + i * 16 + (lane & 15)) * 32 + (lane >> 4) * 8];
#pragma unroll
    for (int i = 0; i < 4; ++i)
      b[i] = *(const bf16x8*)&Bs[(wn + i * 16 + (lane & 15)) * 32 + (lane >> 4) * 8];
#pragma unroll
    for (int mi = 0; mi < 4; ++mi)
#pragma unroll
      for (int ni = 0; ni < 4; ++ni)
        acc[mi][ni] = __builtin_amdgcn_mfma_f32_16x16x32_bf16(a[mi], b[ni], acc[mi][ni], 0, 0, 0);
  }

  // epilogue: C[row=(lane>>4)*4+r][col=lane&15] per 16x16 subtile
#pragma unroll
  for (int mi = 0; mi < 4; ++mi) {
    const int row = m0 + wm + mi * 16 + (lane >> 4) * 4;
#pragma unroll
    for (int ni = 0; ni < 4; ++ni) {
      const int col = n0 + wn + ni * 16 + (lane & 15);
      const float bv = bias[col];
#pragma unroll
      for (int r = 0; r < 4; ++r)
        Y[(size_t)(row + r) * N + col] = (TY)(acc[mi][ni][r] + bv);
    }
  }
}

// ---------------------------------------------------------------------------
// Flash attention, causal. Q/K/V/O in [B*S, H] bf16, head h = cols h*64..h*64+63.
// Block: 256 threads (4 waves). Q-tile = 128 rows; wave owns 32 rows (2 m-blocks).
// k-tiles of 64 keys, kt = 0..2qt+1. All LDS tiles padded to stride ST=72.
// ---------------------------------------------------------------------------
__global__ __launch_bounds__(256) void attn_causal(
    const bf16* __restrict__ Q, const bf16* __restrict__ K,
    const bf16* __restrict__ V, bf16* __restrict__ O)
{
  const int qt = (int)(gridDim.x - 1) - (int)blockIdx.x;   // heavy tiles first
  const int bh = blockIdx.y;
  const int b  = bh >> 4;
  const int h  = bh & 15;

  const int tid  = threadIdx.x;
  const int lane = tid & 63;
  const int wave = tid >> 6;
  const int quad = lane >> 4;
  const int l15  = lane & 15;
  const size_t headoff = (size_t)b * S_ * H_ + (size_t)h * HD_;
  const int q0 = qt * 128;

  __shared__ __align__(16) bf16 Qs[128 * ST];     // 18432 B
  __shared__ __align__(16) bf16 Ks[64 * ST];      //  9216 B
  __shared__ __align__(16) bf16 Vt[64 * ST];      //  9216 B  Vt[d][key]
  __shared__ __align__(16) bf16 Ps[4][32 * ST];   // 18432 B  per-wave P tile

  // stage Q once: 128x64 = 1024 8-elem chunks, 4 per thread
#pragma unroll
  for (int it = 0; it < 4; ++it) {
    const int c = it * 256 + tid, row = c >> 3, col = (c & 7) * 8;
    *(bf16x8*)&Qs[row * ST + col] =
        *(const bf16x8*)(Q + headoff + (size_t)(q0 + row) * H_ + col);
  }

  float mrow[2][4], lrow[2][4];
  f32x4 oacc[2][4] = {};
#pragma unroll
  for (int mi = 0; mi < 2; ++mi)
#pragma unroll
    for (int r = 0; r < 4; ++r) { mrow[mi][r] = -1e30f; lrow[mi][r] = 0.0f; }

  const int ktmax = 2 * qt + 1;
  for (int kt = 0; kt <= ktmax; ++kt) {
    const int k0 = kt * 64;
    __syncthreads();   // prev iter done reading Ks/Vt; Q writes done (iter 0)

    // stage K tile row-major: 512 chunks, 2/thread
#pragma unroll
    for (int it = 0; it < 2; ++it) {
      const int c = it * 256 + tid, row = c >> 3, col = (c & 7) * 8;
      *(bf16x8*)&Ks[row * ST + col] =
          *(const bf16x8*)(K + headoff + (size_t)(k0 + row) * H_ + col);
    }
    // stage V transposed: thread handles 2 key-rows x 8 d; paired b32 writes.
    // row=(tid&31)*2 -> 32 lanes sweep banks; 2-way alias across tid>>5 (free).
    {
      const int row = (tid & 31) * 2;
      const int col = (tid >> 5) * 8;
      bf16x8 r0 = *(const bf16x8*)(V + headoff + (size_t)(k0 + row) * H_ + col);
      bf16x8 r1 = *(const bf16x8*)(V + headoff + (size_t)(k0 + row + 1) * H_ + col);
#pragma unroll
      for (int e = 0; e < 8; ++e) {
        bf16x2 p; p[0] = r0[e]; p[1] = r1[e];
        *(bf16x2*)&Vt[(col + e) * ST + row] = p;
      }
    }
    __syncthreads();

    // last diagonal tile: waves 0,1 (rows q0..q0+63 < keys) fully masked -> skip
    if (!(kt == ktmax && wave < 2)) {
      const int rb = wave * 32;                  // wave's row base in q-tile

      // ---- S = Q K^T : 2 m-blocks x 4 n-blocks ----
      f32x4 sacc[2][4] = {};
#pragma unroll
      for (int ks = 0; ks < 2; ++ks) {
        bf16x8 aq[2];
#pragma unroll
        for (int mi = 0; mi < 2; ++mi)
          aq[mi] = *(const bf16x8*)&Qs[(rb + mi * 16 + l15) * ST + ks * 32 + quad * 8];
#pragma unroll
        for (int ni = 0; ni < 4; ++ni) {
          bf16x8 bk = *(const bf16x8*)&Ks[(ni * 16 + l15) * ST + ks * 32 + quad * 8];
          sacc[0][ni] = __builtin_amdgcn_mfma_f32_16x16x32_bf16(aq[0], bk, sacc[0][ni], 0, 0, 0);
          sacc[1][ni] = __builtin_amdgcn_mfma_f32_16x16x32_bf16(aq[1], bk, sacc[1][ni], 0, 0, 0);
        }
      }

      const bool needmask = (kt >= 2 * qt);
#pragma unroll
      for (int mi = 0; mi < 2; ++mi) {
        const int qrow0 = q0 + rb + mi * 16 + quad * 4;   // global q row base
        float sv[4][4];
#pragma unroll
        for (int ni = 0; ni < 4; ++ni) {
          const int kcol = k0 + ni * 16 + l15;
#pragma unroll
          for (int r = 0; r < 4; ++r) {
            const float s = sacc[mi][ni][r] * 0.125f;     // 1/sqrt(64)
            sv[ni][r] = (needmask && kcol > qrow0 + r) ? -1e30f : s;
          }
        }
        // online softmax per row (16 lanes of this quad hold the row)
#pragma unroll
        for (int r = 0; r < 4; ++r) {
          float mx = fmaxf(fmaxf(sv[0][r], sv[1][r]), fmaxf(sv[2][r], sv[3][r]));
#pragma unroll
          for (int off = 8; off >= 1; off >>= 1)
            mx = fmaxf(mx, __shfl_xor(mx, off, 64));
          const float mnew  = fmaxf(mrow[mi][r], mx);
          const float alpha = __expf(mrow[mi][r] - mnew);
          float sum = 0.0f;
#pragma unroll
          for (int ni = 0; ni < 4; ++ni) {
            const float p = __expf(sv[ni][r] - mnew);
            sv[ni][r] = p;
            sum += p;
          }
#pragma unroll
          for (int off = 8; off >= 1; off >>= 1)
            sum += __shfl_xor(sum, off, 64);
          lrow[mi][r] = lrow[mi][r] * alpha + sum;
          mrow[mi][r] = mnew;
#pragma unroll
          for (int dt = 0; dt < 4; ++dt) oacc[mi][dt][r] *= alpha;
        }
        // P: C-layout -> A-layout via per-wave LDS round trip (same-wave, in-order)
#pragma unroll
        for (int ni = 0; ni < 4; ++ni)
#pragma unroll
          for (int r = 0; r < 4; ++r)
            Ps[wave][(mi * 16 + quad * 4 + r) * ST + ni * 16 + l15] = (bf16)sv[ni][r];
      }

      // ---- O += P V ----
#pragma unroll
      for (int ks = 0; ks < 2; ++ks) {
        bf16x8 ap[2];
#pragma unroll
        for (int mi = 0; mi < 2; ++mi)
          ap[mi] = *(const bf16x8*)&Ps[wave][(mi * 16 + l15) * ST + ks * 32 + quad * 8];
#pragma unroll
        for (int dt = 0; dt < 4; ++dt) {
          bf16x8 bv = *(const bf16x8*)&Vt[(dt * 16 + l15) * ST + ks * 32 + quad * 8];
          oacc[0][dt] = __builtin_amdgcn_mfma_f32_16x16x32_bf16(ap[0], bv, oacc[0][dt], 0, 0, 0);
          oacc[1][dt] = __builtin_amdgcn_mfma_f32_16x16x32_bf16(ap[1], bv, oacc[1][dt], 0, 0, 0);
        }
      }
    }
  }

  // epilogue: O /= l, store
#pragma unroll
  for (int mi = 0; mi < 2; ++mi)
#pragma unroll
    for (int r = 0; r < 4; ++r) {
      const float inv = 1.0f / lrow[mi][r];
      const int s = q0 + wave * 32 + mi * 16 + quad * 4 + r;
#pragma unroll
      for (int dt = 0; dt < 4; ++dt) {
        const int d = dt * 16 + l15;
        O[headoff + (size_t)s * H_ + d] = (bf16)(oacc[mi][dt][r] * inv);
      }
    }
}

extern "C" void kernel_launch(void* const* d_in, const int* in_sizes, int n_in,
                              void* d_out, int out_size, void* d_ws, size_t ws_size,
                              hipStream_t stream) {
  // inputs fp32 (reference dtype); output fp32 (reference output dtype)
  const float* hs = (const float*)d_in[0];
  const float* Wq = (const float*)d_in[1]; const float* bq = (const float*)d_in[2];
  const float* Wk = (const float*)d_in[3]; const float* bk = (const float*)d_in[4];
  const float* Wv = (const float*)d_in[5]; const float* bv = (const float*)d_in[6];
  const float* Wo = (const float*)d_in[7]; const float* bo = (const float*)d_in[8];
  float* out = (float*)d_out;

  const size_t elems = (size_t)B_ * S_ * H_;   // 4,194,304
  bf16* Qw = (bf16*)d_ws;                      // 32 MB workspace (bf16 internal)
  bf16* Kw = Qw + elems;
  bf16* Vw = Kw + elems;
  bf16* AO = Vw + elems;

  const int M = B_ * S_;   // 4096
  // QKV projections (z selects Q/K/V); fp32 in, bf16 out
  gemm_bt_bias<float, bf16><<<dim3(H_ / 128, M / 128, 3), dim3(256), 0, stream>>>(
      hs, Wq, Wk, Wv, bq, bk, bv, Qw, Kw, Vw, M, H_, H_);

  // causal flash attention (bf16 in/out), 128-row q-tiles
  attn_causal<<<dim3(S_ / 128, B_ * NH_), dim3(256), 0, stream>>>(Qw, Kw, Vw, AO);

  // output projection: bf16 activations, fp32 weights, fp32 output
  gemm_bt_bias<bf16, float><<<dim3(H_ / 128, M / 128, 1), dim3(256), 0, stream>>>(
      AO, Wo, Wo, Wo, bo, bo, bo, out, out, out, M, H_, H_);
}

// Round 7
// 205.560 us; speedup vs baseline: 1.6791x; 1.3807x over previous
//
#include <hip/hip_runtime.h>
#include <stdint.h>

typedef __bf16 bf16;
typedef __attribute__((ext_vector_type(2))) __bf16 bf16x2;
typedef __attribute__((ext_vector_type(4))) __bf16 bf16x4;
typedef __attribute__((ext_vector_type(8))) __bf16 bf16x8;
typedef __attribute__((ext_vector_type(4))) float f32x4;

#define B_  2
#define S_  2048
#define H_  1024
#define NH_ 16
#define HD_ 64
#define ST  72    // Qs/Ks hd-stride (rows of 64 + 8 pad)
#define STV 136   // Vt/Ps key-stride (128 keys + 8 pad)

// ---------------------------------------------------------------------------
// fp32 -> bf16 conversion: y=0 hidden_states, y=1..4 weight matrices.
// ---------------------------------------------------------------------------
__global__ __launch_bounds__(256) void cvt_f32_bf16(
    const float* __restrict__ s0, bf16* __restrict__ d0, int n0,
    const float* __restrict__ s1, bf16* __restrict__ d1,
    const float* __restrict__ s2, bf16* __restrict__ d2,
    const float* __restrict__ s3, bf16* __restrict__ d3,
    const float* __restrict__ s4, bf16* __restrict__ d4, int nw)
{
  const float* s; bf16* d; int n;
  switch (blockIdx.y) {
    case 0:  s = s0; d = d0; n = n0; break;
    case 1:  s = s1; d = d1; n = nw; break;
    case 2:  s = s2; d = d2; n = nw; break;
    case 3:  s = s3; d = d3; n = nw; break;
    default: s = s4; d = d4; n = nw; break;
  }
  const int i = (blockIdx.x * 256 + threadIdx.x) * 8;
  if (i >= n) return;
  float4 v0 = *(const float4*)(s + i);
  float4 v1 = *(const float4*)(s + i + 4);
  bf16x8 o;
  o[0] = (bf16)v0.x; o[1] = (bf16)v0.y; o[2] = (bf16)v0.z; o[3] = (bf16)v0.w;
  o[4] = (bf16)v1.x; o[5] = (bf16)v1.y; o[6] = (bf16)v1.z; o[7] = (bf16)v1.w;
  *(bf16x8*)(d + i) = o;
}

// ---------------------------------------------------------------------------
// GEMM: Y[m,n] = sum_k X[m,k]*W[n,k] + bias[n], all-bf16 inputs, fp32 bias.
// 128x128 tile, BK=32, register prefetch overlapping MFMA.
// ---------------------------------------------------------------------------
template <typename TY>
__global__ __launch_bounds__(256) void gemm_bt_bias(
    const bf16* __restrict__ X,
    const bf16* __restrict__ W0, const bf16* __restrict__ W1, const bf16* __restrict__ W2,
    const float* __restrict__ b0, const float* __restrict__ b1, const float* __restrict__ b2,
    TY* __restrict__ Y0, TY* __restrict__ Y1, TY* __restrict__ Y2,
    int M, int N, int K)
{
  const bf16* W; const float* bias; TY* Y;
  if (blockIdx.z == 0)      { W = W0; bias = b0; Y = Y0; }
  else if (blockIdx.z == 1) { W = W1; bias = b1; Y = Y1; }
  else                      { W = W2; bias = b2; Y = Y2; }

  __shared__ __align__(16) bf16 As[128 * 32];
  __shared__ __align__(16) bf16 Bs[128 * 32];

  const int tid  = threadIdx.x;
  const int lane = tid & 63;
  const int wave = tid >> 6;
  const int m0 = blockIdx.y * 128;
  const int n0 = blockIdx.x * 128;
  const int wm = (wave >> 1) * 64;
  const int wn = (wave & 1) * 64;

  f32x4 acc[4][4] = {};
  bf16x8 pa[2], pb[2];

#pragma unroll
  for (int it = 0; it < 2; ++it) {
    const int c = it * 256 + tid, row = c >> 2, col = (c & 3) * 8;
    pa[it] = *(const bf16x8*)(X + (size_t)(m0 + row) * K + col);
    pb[it] = *(const bf16x8*)(W + (size_t)(n0 + row) * K + col);
  }

  for (int k0 = 0; k0 < K; k0 += 32) {
    __syncthreads();
#pragma unroll
    for (int it = 0; it < 2; ++it) {
      const int c = it * 256 + tid, row = c >> 2, col = (c & 3) * 8;
      *(bf16x8*)&As[row * 32 + col] = pa[it];
      *(bf16x8*)&Bs[row * 32 + col] = pb[it];
    }
    __syncthreads();

    if (k0 + 32 < K) {
#pragma unroll
      for (int it = 0; it < 2; ++it) {
        const int c = it * 256 + tid, row = c >> 2, col = (c & 3) * 8;
        pa[it] = *(const bf16x8*)(X + (size_t)(m0 + row) * K + k0 + 32 + col);
        pb[it] = *(const bf16x8*)(W + (size_t)(n0 + row) * K + k0 + 32 + col);
      }
    }

    bf16x8 a[4], b[4];
#pragma unroll
    for (int i = 0; i < 4; ++i)
      a[i] = *(const bf16x8*)&As[(wm + i * 16 + (lane & 15)) * 32 + (lane >> 4) * 8];
#pragma unroll
    for (int i = 0; i < 4; ++i)
      b[i] = *(const bf16x8*)&Bs[(wn + i * 16 + (lane & 15)) * 32 + (lane >> 4) * 8];
#pragma unroll
    for (int mi = 0; mi < 4; ++mi)
#pragma unroll
      for (int ni = 0; ni < 4; ++ni)
        acc[mi][ni] = __builtin_amdgcn_mfma_f32_16x16x32_bf16(a[mi], b[ni], acc[mi][ni], 0, 0, 0);
  }

#pragma unroll
  for (int mi = 0; mi < 4; ++mi) {
    const int row = m0 + wm + mi * 16 + (lane >> 4) * 4;
#pragma unroll
    for (int ni = 0; ni < 4; ++ni) {
      const int col = n0 + wn + ni * 16 + (lane & 15);
      const float bv = bias[col];
#pragma unroll
      for (int r = 0; r < 4; ++r)
        Y[(size_t)(row + r) * N + col] = (TY)(acc[mi][ni][r] + bv);
    }
  }
}

// ---------------------------------------------------------------------------
// Flash attention, causal, transposed-score orientation.
// Block: 256 thr (4 waves). Processes TWO 64-row q-tiles (qt, 31-qt) -> every
// block does exactly 17 x 128-key iterations (balanced). Wave owns 16 q-rows;
// lane's row = l15 (S^T C-layout col). Softmax = in-lane trees + 2 shuffles.
// ---------------------------------------------------------------------------
__global__ __launch_bounds__(256) void attn_causal(
    const bf16* __restrict__ Q, const bf16* __restrict__ K,
    const bf16* __restrict__ V, bf16* __restrict__ O)
{
  const int pair = blockIdx.x;         // 0..15
  const int bh   = blockIdx.y;         // 0..31
  const int b    = bh >> 4;
  const int h    = bh & 15;

  const int tid  = threadIdx.x;
  const int lane = tid & 63;
  const int wave = tid >> 6;
  const int quad = lane >> 4;
  const int l15  = lane & 15;
  const size_t headoff = (size_t)b * S_ * H_ + (size_t)h * HD_;

  __shared__ __align__(16) bf16 Qs[64 * ST];        //  9216 B
  __shared__ __align__(16) bf16 Ks[128 * ST];       // 18432 B
  __shared__ __align__(16) bf16 Vt[64 * STV];       // 17408 B  Vt[d][key]
  __shared__ __align__(16) bf16 Ps[4][16 * STV];    // 17408 B  P[qrow][key] per wave

  for (int phase = 0; phase < 2; ++phase) {
    const int qt = phase ? (31 - pair) : pair;
    const int q0 = qt * 64;
    __syncthreads();   // prior phase done reading Qs

    // stage Q tile: 64x64 = 512 chunks, 2/thread
#pragma unroll
    for (int it = 0; it < 2; ++it) {
      const int c = it * 256 + tid, row = c >> 3, col = (c & 7) * 8;
      *(bf16x8*)&Qs[row * ST + col] =
          *(const bf16x8*)(Q + headoff + (size_t)(q0 + row) * H_ + col);
    }

    const int qrow = q0 + wave * 16 + l15;   // this lane's q-row
    float mr = -1e30f, lr = 0.0f;
    f32x4 oacc[4] = {};

    const int niter = (qt >> 1) + 1;         // ceil((qt+1)/2) 128-key tiles
    for (int it = 0; it < niter; ++it) {
      const int k0 = it * 128;
      __syncthreads();   // prev iter reads done; Qs writes visible (it==0)

      // stage K tile 128x64: 1024 chunks, 4/thread
#pragma unroll
      for (int j = 0; j < 4; ++j) {
        const int c = j * 256 + tid, row = c >> 3, col = (c & 7) * 8;
        *(bf16x8*)&Ks[row * ST + col] =
            *(const bf16x8*)(K + headoff + (size_t)(k0 + row) * H_ + col);
      }
      // stage V transposed: thread: key-rows vr,vr+1, d-cols vc..vc+15
      {
        const int vr = (tid & 63) * 2;
        const int vc = (tid >> 6) * 16;
        bf16x8 a0 = *(const bf16x8*)(V + headoff + (size_t)(k0 + vr) * H_ + vc);
        bf16x8 a1 = *(const bf16x8*)(V + headoff + (size_t)(k0 + vr) * H_ + vc + 8);
        bf16x8 c0 = *(const bf16x8*)(V + headoff + (size_t)(k0 + vr + 1) * H_ + vc);
        bf16x8 c1 = *(const bf16x8*)(V + headoff + (size_t)(k0 + vr + 1) * H_ + vc + 8);
#pragma unroll
        for (int e = 0; e < 8; ++e) {
          bf16x2 p0; p0[0] = a0[e]; p0[1] = c0[e];
          *(bf16x2*)&Vt[(vc + e) * STV + vr] = p0;
          bf16x2 p1; p1[0] = a1[e]; p1[1] = c1[e];
          *(bf16x2*)&Vt[(vc + 8 + e) * STV + vr] = p1;
        }
      }
      __syncthreads();

      // ---- S^T = K Q^T : 8 key-blocks x (this wave's 16 q-rows) ----
      f32x4 sacc[8] = {};
#pragma unroll
      for (int ks = 0; ks < 2; ++ks) {
        bf16x8 bq = *(const bf16x8*)&Qs[(wave * 16 + l15) * ST + ks * 32 + quad * 8];
#pragma unroll
        for (int mb = 0; mb < 8; ++mb) {
          bf16x8 ak = *(const bf16x8*)&Ks[(mb * 16 + l15) * ST + ks * 32 + quad * 8];
          sacc[mb] = __builtin_amdgcn_mfma_f32_16x16x32_bf16(ak, bq, sacc[mb], 0, 0, 0);
        }
      }

      // scale + causal mask; all 32 values belong to row `qrow`
      float sv[8][4];
#pragma unroll
      for (int mb = 0; mb < 8; ++mb) {
        const int kb = k0 + mb * 16 + quad * 4;
#pragma unroll
        for (int r = 0; r < 4; ++r) {
          const float s = sacc[mb][r] * 0.125f;     // 1/sqrt(64)
          sv[mb][r] = (kb + r > qrow) ? -1e30f : s;
        }
      }

      // row max: in-lane tree + 2 shuffles (quads hold different keys)
      float mx = -1e30f;
#pragma unroll
      for (int mb = 0; mb < 8; ++mb)
        mx = fmaxf(mx, fmaxf(fmaxf(sv[mb][0], sv[mb][1]), fmaxf(sv[mb][2], sv[mb][3])));
      mx = fmaxf(mx, __shfl_xor(mx, 16, 64));
      mx = fmaxf(mx, __shfl_xor(mx, 32, 64));
      const float mnew  = fmaxf(mr, mx);
      const float alpha = __expf(mr - mnew);
      mr = mnew;

      // exp, P write (b64 contiguous), sum
      float sum = 0.0f;
#pragma unroll
      for (int mb = 0; mb < 8; ++mb) {
        bf16x4 pw;
#pragma unroll
        for (int r = 0; r < 4; ++r) {
          const float p = __expf(sv[mb][r] - mnew);
          sum += p;
          pw[r] = (bf16)p;
        }
        *(bf16x4*)&Ps[wave][l15 * STV + mb * 16 + quad * 4] = pw;
      }
      sum += __shfl_xor(sum, 16, 64);
      sum += __shfl_xor(sum, 32, 64);
      lr = lr * alpha + sum;
#pragma unroll
      for (int mb = 0; mb < 4; ++mb)
#pragma unroll
        for (int r = 0; r < 4; ++r) oacc[mb][r] *= alpha;

      // ---- O^T += V^T P^T : 4 d-blocks, K-dim = 128 keys ----
#pragma unroll
      for (int ks = 0; ks < 4; ++ks) {
        bf16x8 bp = *(const bf16x8*)&Ps[wave][l15 * STV + ks * 32 + quad * 8];
#pragma unroll
        for (int mb = 0; mb < 4; ++mb) {
          bf16x8 av = *(const bf16x8*)&Vt[(mb * 16 + l15) * STV + ks * 32 + quad * 8];
          oacc[mb] = __builtin_amdgcn_mfma_f32_16x16x32_bf16(av, bp, oacc[mb], 0, 0, 0);
        }
      }
    }

    // epilogue: lane's row = qrow; d = mb*16 + quad*4 + r  -> b64 stores
    const float inv = 1.0f / lr;
#pragma unroll
    for (int mb = 0; mb < 4; ++mb) {
      bf16x4 o;
#pragma unroll
      for (int r = 0; r < 4; ++r) o[r] = (bf16)(oacc[mb][r] * inv);
      *(bf16x4*)(O + headoff + (size_t)qrow * H_ + mb * 16 + quad * 4) = o;
    }
  }
}

extern "C" void kernel_launch(void* const* d_in, const int* in_sizes, int n_in,
                              void* d_out, int out_size, void* d_ws, size_t ws_size,
                              hipStream_t stream) {
  const float* hs = (const float*)d_in[0];
  const float* Wq = (const float*)d_in[1]; const float* bq = (const float*)d_in[2];
  const float* Wk = (const float*)d_in[3]; const float* bk = (const float*)d_in[4];
  const float* Wv = (const float*)d_in[5]; const float* bv = (const float*)d_in[6];
  const float* Wo = (const float*)d_in[7]; const float* bo = (const float*)d_in[8];
  float* out = (float*)d_out;

  const size_t elems = (size_t)B_ * S_ * H_;   // 4,194,304
  const size_t wel   = (size_t)H_ * H_;        // 1,048,576
  // workspace (40 MB): [hsb | AO aliased 8MB][W bf16 8MB][Q 8][K 8][V 8]
  bf16* hsb = (bf16*)d_ws;      // read only by QKV GEMM
  bf16* AO  = hsb;              // written by attn (after hsb is dead)
  bf16* Wqb = hsb + elems;
  bf16* Wkb = Wqb + wel;
  bf16* Wvb = Wkb + wel;
  bf16* Wob = Wvb + wel;
  bf16* Qw  = Wob + wel;
  bf16* Kw  = Qw + elems;
  bf16* Vw  = Kw + elems;

  // fp32 -> bf16: hidden_states + 4 weights
  cvt_f32_bf16<<<dim3(2048, 5), dim3(256), 0, stream>>>(
      hs, hsb, (int)elems, Wq, Wqb, Wk, Wkb, Wv, Wvb, Wo, Wob, (int)wel);

  const int M = B_ * S_;   // 4096
  // QKV projections (all-bf16)
  gemm_bt_bias<bf16><<<dim3(H_ / 128, M / 128, 3), dim3(256), 0, stream>>>(
      hsb, Wqb, Wkb, Wvb, bq, bk, bv, Qw, Kw, Vw, M, H_, H_);

  // causal flash attention, paired 64-row q-tiles (perfect balance)
  attn_causal<<<dim3(16, B_ * NH_), dim3(256), 0, stream>>>(Qw, Kw, Vw, AO);

  // output projection: bf16 x bf16 -> fp32 out
  gemm_bt_bias<float><<<dim3(H_ / 128, M / 128, 1), dim3(256), 0, stream>>>(
      AO, Wob, Wob, Wob, bo, bo, bo, out, out, out, M, H_, H_);
}